// Round 8
// baseline (431.757 us; speedup 1.0000x reference)
//
#include <hip/hip_runtime.h>

// R8 = DIAGNOSTIC: exact R7 body executed TWICE per dispatch (single kernel,
// outer pass loop) so the dispatch (~455 us) outranks the harness's ~315 us
// fills and finally appears in the rocprof top-5 with VGPR_Count /
// OccupancyPercent / FETCH / WRITE / MfmaUtil / VALUBusy / bank conflicts.
// R4-R7 all plateau at 228-242 us (~4.9 TB/s vs 6.6 proven) and every
// experiment was confounded by unmeasured register count -> buy evidence.
// Deterministic: pass 2 recomputes identical outputs.
//
// Body (R7): W fragments (32 KB) + bias (exact f32) in LDS shared by the
// block's 4 waves; model-interleaved token order (each model's 64 waves sweep
// one contiguous 256-KB window per step); depth-1 register prefetch.
// Orientation: D[f][tok]; k-map k = 32*kk + 16*(j>>2) + 4*g + (j&3) for both
// operands; C/D: col=lane&15=token, row=4*(lane>>4)+reg=feature.

typedef __attribute__((ext_vector_type(8))) _Float16 f16x8;
typedef __attribute__((ext_vector_type(2))) __fp16 fp16x2; // cvt_pkrtz's native type
typedef __attribute__((ext_vector_type(4))) float f32x4;

#define MODELS 64
#define LAYERS 4
#define DIM 64
#define TOKS_PER_MODEL 32768
#define BLOCKS_PER_MODEL 16
#define WAVES_PER_BLOCK 4
#define WAVES_PER_MODEL (BLOCKS_PER_MODEL * WAVES_PER_BLOCK)    // 64
#define STEPS 32                                                 // tiles per wave
#define STEP_FLOATS ((size_t)WAVES_PER_MODEL * 16 * DIM)         // 65536 (256 KB)

#define WF_BYTES (LAYERS * 4 * 2 * 64 * 16)       // 32768: [l][t][kk][lane] f16x8
#define BIAS_OFF WF_BYTES                          // [l][64] f32
#define LDS_BYTES (WF_BYTES + LAYERS * DIM * 4)    // 33792

union H8 { f16x8 v; fp16x2 h2[4]; };

__global__ __launch_bounds__(256, 2) void mlp4_fused(
    const float* __restrict__ x, const float* __restrict__ W,
    const float* __restrict__ b, float* __restrict__ out) {

    __shared__ __align__(16) unsigned char smem[LDS_BYTES];

    const int lane = threadIdx.x & 63;
    const int wave = threadIdx.x >> 6;
    const int c = lane & 15;   // token column (B/D) and W feature row (A)
    const int g = lane >> 4;   // k-group

    const int m   = blockIdx.x / BLOCKS_PER_MODEL;
    const int blk = blockIdx.x % BLOCKS_PER_MODEL;
    const int q   = blk * WAVES_PER_BLOCK + wave;   // wave index within model, 0..63

    // ---- stage this wave's layer (l = wave) of W into LDS ----
    // wf[l][t][kk] element j = f16(W[m][l][16t + c][32kk + 16*(j>>2) + 4g + (j&3)])
    {
        const int l = wave;
        const float* Wl = W + ((size_t)m * LAYERS + l) * DIM * DIM;
        #pragma unroll
        for (int t = 0; t < 4; ++t) {
            const float* row = Wl + (size_t)(t * 16 + c) * DIM + 4 * g;
            f32x4 c0 = *(const f32x4*)(row + 0);
            f32x4 c1 = *(const f32x4*)(row + 16);
            f32x4 c2 = *(const f32x4*)(row + 32);
            f32x4 c3 = *(const f32x4*)(row + 48);
            H8 a0, a1;
            #pragma unroll
            for (int e = 0; e < 4; ++e) {
                a0.v[e]     = (_Float16)c0[e];  // RNE for weights (one-time)
                a0.v[4 + e] = (_Float16)c1[e];
                a1.v[e]     = (_Float16)c2[e];
                a1.v[4 + e] = (_Float16)c3[e];
            }
            *(f16x8*)(smem + ((size_t)((l * 4 + t) * 2 + 0) * 1024) + lane * 16) = a0.v;
            *(f16x8*)(smem + ((size_t)((l * 4 + t) * 2 + 1) * 1024) + lane * 16) = a1.v;
        }
        // bias layer l, exact f32: 64 floats
        if (lane < 16) {
            const float* bl = b + ((size_t)m * LAYERS + l) * DIM + lane * 4;
            *(f32x4*)(smem + BIAS_OFF + l * 256 + lane * 16) = *(const f32x4*)bl;
        }
    }
    __syncthreads();

    // Lane's base: model m, wave-slot q's 16 tokens, token (q*16 + c), col 4g.
    const float* xp = x   + ((size_t)m * TOKS_PER_MODEL + (size_t)q * 16) * DIM
                          + (size_t)(c * DIM + 4 * g);
    float*       op = out + ((size_t)m * TOKS_PER_MODEL + (size_t)q * 16) * DIM
                          + (size_t)(c * DIM + 4 * g);

    #pragma unroll 1
    for (int pass = 0; pass < 2; ++pass) {   // DIAGNOSTIC double-pass
        f32x4 xr0 = *(const f32x4*)(xp + 0);
        f32x4 xr1 = *(const f32x4*)(xp + 16);
        f32x4 xr2 = *(const f32x4*)(xp + 32);
        f32x4 xr3 = *(const f32x4*)(xp + 48);

        #pragma unroll 1
        for (int s = 0; s < STEPS; ++s) {
            // register-double-buffered prefetch of next step's x (+256 KB stride)
            const int nxt = (s + 1) & (STEPS - 1);
            const float* nx = xp + (size_t)nxt * STEP_FLOATS;
            f32x4 xn0 = *(const f32x4*)(nx + 0);
            f32x4 xn1 = *(const f32x4*)(nx + 16);
            f32x4 xn2 = *(const f32x4*)(nx + 32);
            f32x4 xn3 = *(const f32x4*)(nx + 48);

            // layer-0 B fragments from current x registers (packed cvt, RTZ)
            H8 z0u, z1u;
            z0u.h2[0] = __builtin_amdgcn_cvt_pkrtz(xr0[0], xr0[1]);
            z0u.h2[1] = __builtin_amdgcn_cvt_pkrtz(xr0[2], xr0[3]);
            z0u.h2[2] = __builtin_amdgcn_cvt_pkrtz(xr1[0], xr1[1]);
            z0u.h2[3] = __builtin_amdgcn_cvt_pkrtz(xr1[2], xr1[3]);
            z1u.h2[0] = __builtin_amdgcn_cvt_pkrtz(xr2[0], xr2[1]);
            z1u.h2[1] = __builtin_amdgcn_cvt_pkrtz(xr2[2], xr2[3]);
            z1u.h2[2] = __builtin_amdgcn_cvt_pkrtz(xr3[0], xr3[1]);
            z1u.h2[3] = __builtin_amdgcn_cvt_pkrtz(xr3[2], xr3[3]);
            f16x8 z0 = z0u.v, z1 = z1u.v;

            f32x4 acc[4];
            #pragma unroll
            for (int l = 0; l < LAYERS; ++l) {
                #pragma unroll
                for (int t = 0; t < 4; ++t)
                    acc[t] = *(const f32x4*)(smem + BIAS_OFF + l * 256 + t * 64 + g * 16);
                #pragma unroll
                for (int t = 0; t < 4; ++t) {
                    f16x8 w0 = *(const f16x8*)(smem + ((size_t)((l * 4 + t) * 2 + 0) * 1024) + lane * 16);
                    acc[t] = __builtin_amdgcn_mfma_f32_16x16x32_f16(w0, z0, acc[t], 0, 0, 0);
                }
                #pragma unroll
                for (int t = 0; t < 4; ++t) {
                    f16x8 w1 = *(const f16x8*)(smem + ((size_t)((l * 4 + t) * 2 + 1) * 1024) + lane * 16);
                    acc[t] = __builtin_amdgcn_mfma_f32_16x16x32_f16(w1, z1, acc[t], 0, 0, 0);
                }

                if (l < LAYERS - 1) {
                    // next-layer B fragment = in-lane relu+cast repack of acc
                    H8 n0, n1;
                    #pragma unroll
                    for (int t = 0; t < 2; ++t) {
                        n0.h2[t * 2 + 0] = __builtin_amdgcn_cvt_pkrtz(
                            fmaxf(acc[t][0], 0.0f), fmaxf(acc[t][1], 0.0f));
                        n0.h2[t * 2 + 1] = __builtin_amdgcn_cvt_pkrtz(
                            fmaxf(acc[t][2], 0.0f), fmaxf(acc[t][3], 0.0f));
                        n1.h2[t * 2 + 0] = __builtin_amdgcn_cvt_pkrtz(
                            fmaxf(acc[2 + t][0], 0.0f), fmaxf(acc[2 + t][1], 0.0f));
                        n1.h2[t * 2 + 1] = __builtin_amdgcn_cvt_pkrtz(
                            fmaxf(acc[2 + t][2], 0.0f), fmaxf(acc[2 + t][3], 0.0f));
                    }
                    z0 = n0.v;
                    z1 = n1.v;
                }
            }

            // store: f = 16t + 4g + r -> r contiguous -> dwordx4 stores
            float* o = op + (size_t)s * STEP_FLOATS;
            #pragma unroll
            for (int t = 0; t < 4; ++t) {
                f32x4 res;
                #pragma unroll
                for (int r = 0; r < 4; ++r) res[r] = fmaxf(acc[t][r], 0.0f);
                *(f32x4*)(o + t * 16) = res;
            }

            xr0 = xn0; xr1 = xn1; xr2 = xn2; xr3 = xn3;
        }
    }
}

extern "C" void kernel_launch(void* const* d_in, const int* in_sizes, int n_in,
                              void* d_out, int out_size, void* d_ws, size_t ws_size,
                              hipStream_t stream) {
    (void)in_sizes; (void)n_in; (void)out_size; (void)d_ws; (void)ws_size;
    const float* x = (const float*)d_in[0];
    const float* W = (const float*)d_in[1];
    const float* b = (const float*)d_in[2];
    float* out = (float*)d_out;
    mlp4_fused<<<dim3(MODELS * BLOCKS_PER_MODEL), dim3(256), 0, stream>>>(x, W, b, out);
}

// Round 9
// 229.427 us; speedup vs baseline: 1.8819x; 1.8819x over previous
//
#include <hip/hip_runtime.h>

// Fused grouped 4-layer MLP: 64 models × 32768 tokens, d=64, fp32 in/out,
// f16 MFMA (fp32 accumulate) inside.
//
// R9 = R7 body with 512-thread blocks (8 waves), grid 512. R8 diagnostics:
// VGPR=128 (tier edge: R5/R6 were tier-confounded), FETCH/WRITE clean, bank
// conflicts 0, occupancy ~22% ~= 2 blocks/CU although VGPR+LDS permit 4.
// If a per-block cap (2 blocks/CU) is real, 8-wave blocks give 16 waves/CU
// at 2 blocks -> 2x in-flight bytes. Per-wave code, VGPR, LDS layout all
// byte-identical to R7; only block geometry + staging split changed.
//
// W fragments (32 KB) + bias (1 KB, exact f32) in LDS, shared by the block's
// 8 waves (same model). Model-interleaved token order (each model's 64 waves
// sweep one contiguous 256-KB window per step). Orientation: D[f][tok];
// k-map k = 32*kk + 16*(j>>2) + 4*g + (j&3) for both operands; C/D layout:
// col=lane&15=token, row=4*(lane>>4)+reg=feature -> next layer's B fragment
// is a pure in-lane relu+cast repack. No inter-wave comms after staging.

typedef __attribute__((ext_vector_type(8))) _Float16 f16x8;
typedef __attribute__((ext_vector_type(2))) __fp16 fp16x2; // cvt_pkrtz's native type
typedef __attribute__((ext_vector_type(4))) float f32x4;

#define MODELS 64
#define LAYERS 4
#define DIM 64
#define TOKS_PER_MODEL 32768
#define THREADS 512
#define WAVES_PER_BLOCK 8
#define BLOCKS_PER_MODEL 8
#define WAVES_PER_MODEL (BLOCKS_PER_MODEL * WAVES_PER_BLOCK)    // 64
#define STEPS 32                                                 // tiles per wave
#define STEP_FLOATS ((size_t)WAVES_PER_MODEL * 16 * DIM)         // 65536 (256 KB)

#define WF_BYTES (LAYERS * 4 * 2 * 64 * 16)       // 32768: [l][t][kk][lane] f16x8
#define BIAS_OFF WF_BYTES                          // [l][64] f32
#define LDS_BYTES (WF_BYTES + LAYERS * DIM * 4)    // 33792

union H8 { f16x8 v; fp16x2 h2[4]; };

__global__ __launch_bounds__(THREADS, 2) void mlp4_fused(
    const float* __restrict__ x, const float* __restrict__ W,
    const float* __restrict__ b, float* __restrict__ out) {

    __shared__ __align__(16) unsigned char smem[LDS_BYTES];

    const int lane = threadIdx.x & 63;
    const int wave = threadIdx.x >> 6;          // 0..7
    const int c = lane & 15;   // token column (B/D) and W feature row (A)
    const int g = lane >> 4;   // k-group

    const int m   = blockIdx.x / BLOCKS_PER_MODEL;
    const int blk = blockIdx.x % BLOCKS_PER_MODEL;
    const int q   = blk * WAVES_PER_BLOCK + wave;   // wave slot in model, 0..63

    // ---- staging: wave w stages layer (w>>1), t-pair (w&1)*2..+1 ----
    // wf[l][t][kk] element j = f16(W[m][l][16t + c][32kk + 16*(j>>2) + 4g + (j&3)])
    {
        const int l = wave >> 1;
        const int tbase = (wave & 1) * 2;
        const float* Wl = W + ((size_t)m * LAYERS + l) * DIM * DIM;
        #pragma unroll
        for (int ti = 0; ti < 2; ++ti) {
            const int t = tbase + ti;
            const float* row = Wl + (size_t)(t * 16 + c) * DIM + 4 * g;
            f32x4 c0 = *(const f32x4*)(row + 0);
            f32x4 c1 = *(const f32x4*)(row + 16);
            f32x4 c2 = *(const f32x4*)(row + 32);
            f32x4 c3 = *(const f32x4*)(row + 48);
            H8 a0, a1;
            #pragma unroll
            for (int e = 0; e < 4; ++e) {
                a0.v[e]     = (_Float16)c0[e];  // RNE for weights (one-time)
                a0.v[4 + e] = (_Float16)c1[e];
                a1.v[e]     = (_Float16)c2[e];
                a1.v[4 + e] = (_Float16)c3[e];
            }
            *(f16x8*)(smem + ((size_t)((l * 4 + t) * 2 + 0) * 1024) + lane * 16) = a0.v;
            *(f16x8*)(smem + ((size_t)((l * 4 + t) * 2 + 1) * 1024) + lane * 16) = a1.v;
        }
        // bias layer l (staged by even waves), exact f32: 64 floats
        if ((wave & 1) == 0 && lane < 16) {
            const float* bl = b + ((size_t)m * LAYERS + l) * DIM + lane * 4;
            *(f32x4*)(smem + BIAS_OFF + l * 256 + lane * 16) = *(const f32x4*)bl;
        }
    }
    __syncthreads();

    // Lane's base: model m, wave-slot q's 16 tokens, token (q*16 + c), col 4g.
    const float* xp = x   + ((size_t)m * TOKS_PER_MODEL + (size_t)q * 16) * DIM
                          + (size_t)(c * DIM + 4 * g);
    float*       op = out + ((size_t)m * TOKS_PER_MODEL + (size_t)q * 16) * DIM
                          + (size_t)(c * DIM + 4 * g);

    f32x4 xr0 = *(const f32x4*)(xp + 0);
    f32x4 xr1 = *(const f32x4*)(xp + 16);
    f32x4 xr2 = *(const f32x4*)(xp + 32);
    f32x4 xr3 = *(const f32x4*)(xp + 48);

    #pragma unroll 1
    for (int s = 0; s < STEPS; ++s) {
        // register-double-buffered prefetch of next step's x (+256 KB stride)
        const int nxt = (s + 1) & (STEPS - 1);
        const float* nx = xp + (size_t)nxt * STEP_FLOATS;
        f32x4 xn0 = *(const f32x4*)(nx + 0);
        f32x4 xn1 = *(const f32x4*)(nx + 16);
        f32x4 xn2 = *(const f32x4*)(nx + 32);
        f32x4 xn3 = *(const f32x4*)(nx + 48);

        // layer-0 B fragments from current x registers (packed cvt, RTZ)
        H8 z0u, z1u;
        z0u.h2[0] = __builtin_amdgcn_cvt_pkrtz(xr0[0], xr0[1]);
        z0u.h2[1] = __builtin_amdgcn_cvt_pkrtz(xr0[2], xr0[3]);
        z0u.h2[2] = __builtin_amdgcn_cvt_pkrtz(xr1[0], xr1[1]);
        z0u.h2[3] = __builtin_amdgcn_cvt_pkrtz(xr1[2], xr1[3]);
        z1u.h2[0] = __builtin_amdgcn_cvt_pkrtz(xr2[0], xr2[1]);
        z1u.h2[1] = __builtin_amdgcn_cvt_pkrtz(xr2[2], xr2[3]);
        z1u.h2[2] = __builtin_amdgcn_cvt_pkrtz(xr3[0], xr3[1]);
        z1u.h2[3] = __builtin_amdgcn_cvt_pkrtz(xr3[2], xr3[3]);
        f16x8 z0 = z0u.v, z1 = z1u.v;

        f32x4 acc[4];
        #pragma unroll
        for (int l = 0; l < LAYERS; ++l) {
            // init acc with exact f32 bias from LDS (broadcast within 16-lane group)
            #pragma unroll
            for (int t = 0; t < 4; ++t)
                acc[t] = *(const f32x4*)(smem + BIAS_OFF + l * 256 + t * 64 + g * 16);
            #pragma unroll
            for (int t = 0; t < 4; ++t) {
                f16x8 w0 = *(const f16x8*)(smem + ((size_t)((l * 4 + t) * 2 + 0) * 1024) + lane * 16);
                acc[t] = __builtin_amdgcn_mfma_f32_16x16x32_f16(w0, z0, acc[t], 0, 0, 0);
            }
            #pragma unroll
            for (int t = 0; t < 4; ++t) {
                f16x8 w1 = *(const f16x8*)(smem + ((size_t)((l * 4 + t) * 2 + 1) * 1024) + lane * 16);
                acc[t] = __builtin_amdgcn_mfma_f32_16x16x32_f16(w1, z1, acc[t], 0, 0, 0);
            }

            if (l < LAYERS - 1) {
                // next-layer B fragment = in-lane relu+cast repack of acc:
                // z[kk][j] = relu(acc[2kk + (j>>2)][j&3]) ; packed pairs
                H8 n0, n1;
                #pragma unroll
                for (int t = 0; t < 2; ++t) {
                    n0.h2[t * 2 + 0] = __builtin_amdgcn_cvt_pkrtz(
                        fmaxf(acc[t][0], 0.0f), fmaxf(acc[t][1], 0.0f));
                    n0.h2[t * 2 + 1] = __builtin_amdgcn_cvt_pkrtz(
                        fmaxf(acc[t][2], 0.0f), fmaxf(acc[t][3], 0.0f));
                    n1.h2[t * 2 + 0] = __builtin_amdgcn_cvt_pkrtz(
                        fmaxf(acc[2 + t][0], 0.0f), fmaxf(acc[2 + t][1], 0.0f));
                    n1.h2[t * 2 + 1] = __builtin_amdgcn_cvt_pkrtz(
                        fmaxf(acc[2 + t][2], 0.0f), fmaxf(acc[2 + t][3], 0.0f));
                }
                z0 = n0.v;
                z1 = n1.v;
            }
        }

        // store: f = 16t + 4g + r -> r contiguous -> dwordx4 stores
        float* o = op + (size_t)s * STEP_FLOATS;
        #pragma unroll
        for (int t = 0; t < 4; ++t) {
            f32x4 res;
            #pragma unroll
            for (int r = 0; r < 4; ++r) res[r] = fmaxf(acc[t][r], 0.0f);
            *(f32x4*)(o + t * 16) = res;
        }

        xr0 = xn0; xr1 = xn1; xr2 = xn2; xr3 = xn3;
    }
}

extern "C" void kernel_launch(void* const* d_in, const int* in_sizes, int n_in,
                              void* d_out, int out_size, void* d_ws, size_t ws_size,
                              hipStream_t stream) {
    (void)in_sizes; (void)n_in; (void)out_size; (void)d_ws; (void)ws_size;
    const float* x = (const float*)d_in[0];
    const float* W = (const float*)d_in[1];
    const float* b = (const float*)d_in[2];
    float* out = (float*)d_out;
    mlp4_fused<<<dim3(MODELS * BLOCKS_PER_MODEL), dim3(THREADS), 0, stream>>>(x, W, b, out);
}